// Round 1
// baseline (1665.980 us; speedup 1.0000x reference)
//
#include <hip/hip_runtime.h>
#include <math.h>

// Problem constants
#define ST 64      // sequence length T
#define NBAT 64    // batch B
#define ED 256     // embedding dim E
#define HD 512     // hidden dim H
#define G4 2048    // 4*H
#define VO 32000   // vocab
#define LSTM_BLOCKS 64

typedef unsigned int u32;
typedef unsigned short u16;
typedef __bf16 bf16;
typedef bf16 bf16x8 __attribute__((ext_vector_type(8)));
typedef float f32x4 __attribute__((ext_vector_type(4)));

__device__ __forceinline__ float sigm(float x) { return 1.f / (1.f + expf(-x)); }

// ---------------- prep kernels ----------------

__global__ void k_lengths(const int* __restrict__ toks, int* __restrict__ len) {
  int b = threadIdx.x;
  if (b < NBAT) {
    int n = 0;
    for (int t = 0; t < ST; ++t) n += (toks[b * ST + t] != 0) ? 1 : 0;
    len[b] = n;
  }
}

__global__ void k_cast(const float* __restrict__ src, bf16* __restrict__ dst, int n) {
  int i = blockIdx.x * blockDim.x + threadIdx.x;
  if (i < n) dst[i] = (bf16)src[i];
}

__global__ void k_bias(const float* __restrict__ a, const float* __restrict__ b,
                       float* __restrict__ o) {
  int i = blockIdx.x * blockDim.x + threadIdx.x;
  if (i < G4) o[i] = a[i] + b[i];
}

// encX[t][b][e] = emb[toks[b][t]][e]; decX[t][b][e] = emb[t==0 ? 1 : toks[b][t-1]][e]
__global__ void k_gather(const int* __restrict__ toks, const float* __restrict__ emb,
                         bf16* __restrict__ encX, bf16* __restrict__ decX) {
  int i = blockIdx.x * blockDim.x + threadIdx.x;
  if (i >= ST * NBAT * ED) return;
  int e = i % ED;
  int tb = i / ED;
  int b = tb % NBAT;
  int t = tb / NBAT;
  int te = toks[b * ST + t];
  encX[i] = (bf16)emb[te * ED + e];
  int td = (t == 0) ? 1 : toks[b * ST + t - 1];
  decX[i] = (bf16)emb[td * ED + e];
}

// ---------------- persistent LSTM kernel ----------------

// Monotonic-counter grid barrier. cnt/gen live in ws (memset to 0 per launch).
// Release on the fetch_add publishes this block's h-stores (agent scope ->
// XCD-L2 writeback); acquire on the gen load invalidates L1/L2 so post-barrier
// h reads are fresh. 64 blocks <= 256 CUs -> all co-resident, no deadlock.
__device__ __forceinline__ void gbar(u32* cnt, u32* gen, u32 target) {
  __syncthreads();
  if (threadIdx.x == 0) {
    u32 a = __hip_atomic_fetch_add(cnt, 1u, __ATOMIC_ACQ_REL, __HIP_MEMORY_SCOPE_AGENT);
    if (a == target * LSTM_BLOCKS - 1) {
      __hip_atomic_store(gen, target, __ATOMIC_RELEASE, __HIP_MEMORY_SCOPE_AGENT);
    } else {
      while (__hip_atomic_load(gen, __ATOMIC_ACQUIRE, __HIP_MEMORY_SCOPE_AGENT) < target)
        __builtin_amdgcn_s_sleep(2);
    }
  }
  __syncthreads();
}

// Grid: 64 blocks x 512 threads. Block bk owns hidden units u0..u0+7 (u0=8*bk)
// for all 4 gates -> 32 gate columns. Gates tile per step: [64 batch x 32 cols],
// K = 512 (h) + 256 (x). 8 waves: wave w -> m-frag (w&3), n-frag (w>>2).
// Gate col order in the 32: [i*8 | f*8 | g*8 | o*8].
__global__ __launch_bounds__(512, 2) void k_lstm(
    const bf16* __restrict__ encX, const bf16* __restrict__ decX,
    const bf16* __restrict__ WihE, const bf16* __restrict__ WhhE,
    const bf16* __restrict__ WihD, const bf16* __restrict__ WhhD,
    const float* __restrict__ bsumE, const float* __restrict__ bsumD,
    const int* __restrict__ len,
    bf16* __restrict__ hbuf,   // [2][NBAT*HD] double-buffered h (bf16)
    bf16* __restrict__ hs,     // [ST][NBAT][HD] decoder outputs
    u32* bar)                  // [0]=cnt, [64]=gen
{
  // +8 pad per row: stride 1040B/528B -> bank offset 4/row -> 2-way max (free)
  __shared__ __align__(16) bf16 Wr[32][HD + 8];
  __shared__ __align__(16) bf16 Wx[32][ED + 8];
  __shared__ float gl[64][33];

  const int tid  = threadIdx.x;
  const int lane = tid & 63;
  const int wid  = tid >> 6;
  const int wm   = wid & 3;        // m-fragment (batch rows 16*wm..)
  const int wn   = wid >> 2;       // n-fragment (cols 16*wn..), 0..1
  const int u0   = blockIdx.x * 8;
  const int r16  = lane & 15;
  const int kc   = (lane >> 4) * 8;
  const int arow = 16 * wm + r16;  // batch row for A-frags
  const int brow = 16 * wn + r16;  // LDS row for B-frags

  // epilogue mapping: one (batch, unit) pair per thread
  const int eb   = tid >> 3;       // 0..63
  const int eu   = tid & 7;        // 0..7
  const int elen = len[eb];
  const int hidx = eb * HD + u0 + eu;

  for (int phase = 0; phase < 2; ++phase) {
    const bf16* Wih  = phase ? WihD : WihE;
    const bf16* Whh  = phase ? WhhD : WhhE;
    const float* bsum = phase ? bsumD : bsumE;
    const bf16* Xall = phase ? decX : encX;

    // load this block's weight slices into LDS (rows: gate q = n>>3, unit u0+(n&7))
    for (int idx = tid; idx < 32 * HD; idx += 512) {
      int n = idx >> 9, k = idx & (HD - 1);
      Wr[n][k] = Whh[((n >> 3) * HD + u0 + (n & 7)) * HD + k];
    }
    for (int idx = tid; idx < 32 * ED; idx += 512) {
      int n = idx >> 8, k = idx & (ED - 1);
      Wx[n][k] = Wih[((n >> 3) * HD + u0 + (n & 7)) * ED + k];
    }
    const float bia = bsum[0 * HD + u0 + eu];
    const float bif = bsum[1 * HD + u0 + eu];
    const float big = bsum[2 * HD + u0 + eu];
    const float bio = bsum[3 * HD + u0 + eu];
    float c = 0.f;
    __syncthreads();

    for (int t = 0; t < ST; ++t) {
      const int step = phase * ST + t;
      const bf16* hin = hbuf + (step & 1) * (NBAT * HD);
      bf16* hout      = hbuf + ((step & 1) ^ 1) * (NBAT * HD);
      const bf16* xin = Xall + t * (NBAT * ED);

      // gates[b][col] = sum_k h[b][k]*Whh[col][k] + sum_e x[b][e]*Wih[col][e]
      f32x4 acc0 = {0.f, 0.f, 0.f, 0.f};   // h-part
      f32x4 acc1 = {0.f, 0.f, 0.f, 0.f};   // x-part (independent chain for ILP)
      #pragma unroll
      for (int kk = 0; kk < HD / 32; ++kk) {
        bf16x8 av = *(const bf16x8*)(hin + arow * HD + kk * 32 + kc);
        bf16x8 bv = *(const bf16x8*)(&Wr[brow][kk * 32 + kc]);
        acc0 = __builtin_amdgcn_mfma_f32_16x16x32_bf16(av, bv, acc0, 0, 0, 0);
      }
      #pragma unroll
      for (int kk = 0; kk < ED / 32; ++kk) {
        bf16x8 av = *(const bf16x8*)(xin + arow * ED + kk * 32 + kc);
        bf16x8 bv = *(const bf16x8*)(&Wx[brow][kk * 32 + kc]);
        acc1 = __builtin_amdgcn_mfma_f32_16x16x32_bf16(av, bv, acc1, 0, 0, 0);
      }
      #pragma unroll
      for (int r = 0; r < 4; ++r)
        gl[16 * wm + (lane >> 4) * 4 + r][16 * wn + r16] = acc0[r] + acc1[r];
      __syncthreads();

      // elementwise LSTM cell, one (b,u) per thread; c lives in a register
      float gi = gl[eb][eu]      + bia;
      float gf = gl[eb][8 + eu]  + bif;
      float gg = gl[eb][16 + eu] + big;
      float go = gl[eb][24 + eu] + bio;
      bool upd = (phase == 1) || (t < elen);
      float cn = sigm(gf) * c + sigm(gi) * tanhf(gg);
      float hn = sigm(go) * tanhf(cn);
      bf16 hv;
      if (upd) { c = cn; hv = (bf16)hn; } else { hv = hin[hidx]; }
      hout[hidx] = hv;
      if (phase == 1) hs[t * (NBAT * HD) + hidx] = hv;

      if (step < 2 * ST - 1) gbar(bar, bar + 64, step + 1);
    }
  }
}

// ---------------- output projection GEMM ----------------
// logits[b][t][v] = sum_h hs[t][b][h] * lin_W[v][h] + lin_b[v]
// M = ST*NBAT = 4096 (row m = t*64+b), N = VO = 32000, K = HD = 512.
// 128x128 tile, BK=64, 4 waves each owning a 64x64 quadrant (4x4 frags).
__global__ __launch_bounds__(256, 2) void k_logits(
    const bf16* __restrict__ hsb, const bf16* __restrict__ Wb,
    const float* __restrict__ linb, float* __restrict__ out)
{
  __shared__ __align__(16) bf16 As[128][72];  // +8 pad -> conflict-free frag reads
  __shared__ __align__(16) bf16 Bs[128][72];
  const int tid  = threadIdx.x;
  const int lane = tid & 63;
  const int wid  = tid >> 6;
  const int wm   = wid >> 1, wn = wid & 1;
  const int bn   = blockIdx.x * 128;
  const int bm   = blockIdx.y * 128;
  const int r16  = lane & 15, kh = lane >> 4;

  f32x4 acc[4][4];
  #pragma unroll
  for (int i = 0; i < 4; ++i)
    #pragma unroll
    for (int j = 0; j < 4; ++j) acc[i][j] = (f32x4){0.f, 0.f, 0.f, 0.f};

  const int srow = tid >> 3;        // 0..31
  const int scol = (tid & 7) * 8;   // 0..56

  for (int kt = 0; kt < HD / 64; ++kt) {
    __syncthreads();
    #pragma unroll
    for (int p = 0; p < 4; ++p) {
      int row = p * 32 + srow;
      *(bf16x8*)(&As[row][scol]) =
          *(const bf16x8*)(hsb + (size_t)(bm + row) * HD + kt * 64 + scol);
      *(bf16x8*)(&Bs[row][scol]) =
          *(const bf16x8*)(Wb + (size_t)(bn + row) * HD + kt * 64 + scol);
    }
    __syncthreads();
    #pragma unroll
    for (int kk = 0; kk < 2; ++kk) {
      bf16x8 af[4], bfv[4];
      #pragma unroll
      for (int i = 0; i < 4; ++i)
        af[i] = *(const bf16x8*)(&As[64 * wm + 16 * i + r16][kk * 32 + kh * 8]);
      #pragma unroll
      for (int j = 0; j < 4; ++j)
        bfv[j] = *(const bf16x8*)(&Bs[64 * wn + 16 * j + r16][kk * 32 + kh * 8]);
      #pragma unroll
      for (int i = 0; i < 4; ++i)
        #pragma unroll
        for (int j = 0; j < 4; ++j)
          acc[i][j] = __builtin_amdgcn_mfma_f32_16x16x32_bf16(af[i], bfv[j], acc[i][j], 0, 0, 0);
    }
  }

  #pragma unroll
  for (int j = 0; j < 4; ++j) {
    int ncol = bn + 64 * wn + 16 * j + r16;
    float bias = linb[ncol];
    #pragma unroll
    for (int i = 0; i < 4; ++i) {
      int mbase = bm + 64 * wm + 16 * i + kh * 4;
      #pragma unroll
      for (int r = 0; r < 4; ++r) {
        int m = mbase + r;
        int b = m & 63, t = m >> 6;
        out[(size_t)(b * ST + t) * VO + ncol] = acc[i][j][r] + bias;
      }
    }
  }
}

// ---------------- host ----------------

extern "C" void kernel_launch(void* const* d_in, const int* in_sizes, int n_in,
                              void* d_out, int out_size, void* d_ws, size_t ws_size,
                              hipStream_t stream) {
  const int*   toks = (const int*)d_in[0];
  const float* emb  = (const float*)d_in[1];
  const float* eWih = (const float*)d_in[2];
  const float* eWhh = (const float*)d_in[3];
  const float* ebih = (const float*)d_in[4];
  const float* ebhh = (const float*)d_in[5];
  const float* dWih = (const float*)d_in[6];
  const float* dWhh = (const float*)d_in[7];
  const float* dbih = (const float*)d_in[8];
  const float* dbhh = (const float*)d_in[9];
  const float* linW = (const float*)d_in[10];
  const float* linb = (const float*)d_in[11];
  float* out = (float*)d_out;

  char* ws = (char*)d_ws;
  size_t off = 0;
  auto alloc = [&](size_t bytes) {
    void* p = ws + off;
    off = (off + bytes + 255) & ~(size_t)255;
    return p;
  };
  bf16* encX  = (bf16*)alloc((size_t)ST * NBAT * ED * 2);
  bf16* decX  = (bf16*)alloc((size_t)ST * NBAT * ED * 2);
  bf16* WihEb = (bf16*)alloc((size_t)G4 * ED * 2);
  bf16* WhhEb = (bf16*)alloc((size_t)G4 * HD * 2);
  bf16* WihDb = (bf16*)alloc((size_t)G4 * ED * 2);
  bf16* WhhDb = (bf16*)alloc((size_t)G4 * HD * 2);
  bf16* WbL   = (bf16*)alloc((size_t)VO * HD * 2);
  float* bsumE = (float*)alloc(G4 * 4);
  float* bsumD = (float*)alloc(G4 * 4);
  bf16* hbuf  = (bf16*)alloc((size_t)2 * NBAT * HD * 2);
  bf16* hs    = (bf16*)alloc((size_t)ST * NBAT * HD * 2);
  int*  len   = (int*)alloc(NBAT * 4);
  u32*  bar   = (u32*)alloc(1024);

  hipMemsetAsync(hbuf, 0, (size_t)2 * NBAT * HD * 2, stream);
  hipMemsetAsync(bar, 0, 1024, stream);

  k_lengths<<<1, 64, 0, stream>>>(toks, len);
  k_bias<<<(G4 + 255) / 256, 256, 0, stream>>>(ebih, ebhh, bsumE);
  k_bias<<<(G4 + 255) / 256, 256, 0, stream>>>(dbih, dbhh, bsumD);
  k_cast<<<(G4 * ED + 255) / 256, 256, 0, stream>>>(eWih, WihEb, G4 * ED);
  k_cast<<<(G4 * HD + 255) / 256, 256, 0, stream>>>(eWhh, WhhEb, G4 * HD);
  k_cast<<<(G4 * ED + 255) / 256, 256, 0, stream>>>(dWih, WihDb, G4 * ED);
  k_cast<<<(G4 * HD + 255) / 256, 256, 0, stream>>>(dWhh, WhhDb, G4 * HD);
  k_cast<<<(VO * HD + 255) / 256, 256, 0, stream>>>(linW, WbL, VO * HD);
  k_gather<<<(ST * NBAT * ED + 255) / 256, 256, 0, stream>>>(toks, emb, encX, decX);

  k_lstm<<<LSTM_BLOCKS, 512, 0, stream>>>(encX, decX, WihEb, WhhEb, WihDb, WhhDb,
                                          bsumE, bsumD, len, hbuf, hs, bar);

  k_logits<<<dim3(VO / 128, (ST * NBAT) / 128), 256, 0, stream>>>(hs, WbL, linb, out);
}

// Round 2
// 1417.531 us; speedup vs baseline: 1.1753x; 1.1753x over previous
//
#include <hip/hip_runtime.h>
#include <math.h>

// Problem constants
#define ST 64      // sequence length T
#define NBAT 64    // batch B
#define ED 256     // embedding dim E
#define HD 512     // hidden dim H
#define G4 2048    // 4*H
#define VO 32000   // vocab
#define LSTM_BLOCKS 64

typedef unsigned int u32;
typedef unsigned short u16;
typedef __bf16 bf16;
typedef bf16 bf16x8 __attribute__((ext_vector_type(8)));
typedef float f32x4 __attribute__((ext_vector_type(4)));

__device__ __forceinline__ float sigm(float x) { return 1.f / (1.f + expf(-x)); }

// ---------------- prep kernels ----------------

__global__ void k_lengths(const int* __restrict__ toks, int* __restrict__ len) {
  int b = threadIdx.x;
  if (b < NBAT) {
    int n = 0;
    for (int t = 0; t < ST; ++t) n += (toks[b * ST + t] != 0) ? 1 : 0;
    len[b] = n;
  }
}

__global__ void k_cast(const float* __restrict__ src, bf16* __restrict__ dst, int n) {
  int i = blockIdx.x * blockDim.x + threadIdx.x;
  if (i < n) dst[i] = (bf16)src[i];
}

__global__ void k_bias(const float* __restrict__ a, const float* __restrict__ b,
                       float* __restrict__ o) {
  int i = blockIdx.x * blockDim.x + threadIdx.x;
  if (i < G4) o[i] = a[i] + b[i];
}

// encX[t][b][e] = emb[toks[b][t]][e]; decX[t][b][e] = emb[t==0 ? 1 : toks[b][t-1]][e]
__global__ void k_gather(const int* __restrict__ toks, const float* __restrict__ emb,
                         bf16* __restrict__ encX, bf16* __restrict__ decX) {
  int i = blockIdx.x * blockDim.x + threadIdx.x;
  if (i >= ST * NBAT * ED) return;
  int e = i % ED;
  int tb = i / ED;
  int b = tb % NBAT;
  int t = tb / NBAT;
  int te = toks[b * ST + t];
  encX[i] = (bf16)emb[te * ED + e];
  int td = (t == 0) ? 1 : toks[b * ST + t - 1];
  decX[i] = (bf16)emb[td * ED + e];
}

// ---------------- persistent LSTM kernel ----------------
//
// Flag-based all-to-all barrier (no contended RMW):
//   fire(v):  __syncthreads(); tid0 release-stores flags[myblock] = v.
//             Release orders this thread's prior accesses; the preceding
//             __syncthreads (s_waitcnt vmcnt(0) + s_barrier per wave) has
//             already drained every wave's h-stores to L2, so flag=v
//             publishes the block's step-v output.
//   wait(v):  wave 0: 64 lanes load the 64 flags (relaxed agent atomics —
//             sc bits bypass stale L1/L2) until __all(flag >= v); then one
//             __threadfence() (agent-scope inv) + __syncthreads so all
//             waves' subsequent h-loads see fresh data.
// Double-buffer safety: flag=t+1 is released after the block's reads of
// step-t input, so all-flags>=t+2 implies nobody still reads the buffer
// that step t+2 overwrites.

// Grid: 64 blocks x 512 threads. Block bk owns hidden units u0..u0+7 (u0=8*bk)
// for all 4 gates -> 32 gate columns. Gates tile per step: [64 batch x 32 cols],
// K = 512 (h) + 256 (x). 8 waves: wave w -> m-frag (w&3), n-frag (w>>2).
// Gate col order in the 32: [i*8 | f*8 | g*8 | o*8].
__global__ __launch_bounds__(512, 2) void k_lstm(
    const bf16* __restrict__ encX, const bf16* __restrict__ decX,
    const bf16* __restrict__ WihE, const bf16* __restrict__ WhhE,
    const bf16* __restrict__ WihD, const bf16* __restrict__ WhhD,
    const float* __restrict__ bsumE, const float* __restrict__ bsumD,
    const int* __restrict__ len,
    bf16* __restrict__ hbuf,   // [2][NBAT*HD] double-buffered h (bf16)
    bf16* __restrict__ hs,     // [ST][NBAT][HD] decoder outputs
    u32* flags)                // [64] per-block progress, 16B-spaced
{
  // +8 pad per row: stride 1040B/528B -> bank offset 4/row -> 2-way max (free)
  __shared__ __align__(16) bf16 Wr[32][HD + 8];
  __shared__ __align__(16) bf16 Wx[32][ED + 8];
  __shared__ float gl[64][33];

  const int tid  = threadIdx.x;
  const int lane = tid & 63;
  const int wid  = tid >> 6;
  const int wm   = wid & 3;        // m-fragment (batch rows 16*wm..)
  const int wn   = wid >> 2;       // n-fragment (cols 16*wn..), 0..1
  const int u0   = blockIdx.x * 8;
  const int r16  = lane & 15;
  const int kc   = (lane >> 4) * 8;
  const int arow = 16 * wm + r16;  // batch row for A-frags
  const int brow = 16 * wn + r16;  // LDS row for B-frags

  // epilogue mapping: one (batch, unit) pair per thread
  const int eb   = tid >> 3;       // 0..63
  const int eu   = tid & 7;        // 0..7
  const int elen = len[eb];
  const int hidx = eb * HD + u0 + eu;

  for (int phase = 0; phase < 2; ++phase) {
    const bf16* Wih  = phase ? WihD : WihE;
    const bf16* Whh  = phase ? WhhD : WhhE;
    const float* bsum = phase ? bsumD : bsumE;
    const bf16* Xall = phase ? decX : encX;

    // load this block's weight slices into LDS (rows: gate q = n>>3, unit u0+(n&7))
    for (int idx = tid; idx < 32 * HD; idx += 512) {
      int n = idx >> 9, k = idx & (HD - 1);
      Wr[n][k] = Whh[((n >> 3) * HD + u0 + (n & 7)) * HD + k];
    }
    for (int idx = tid; idx < 32 * ED; idx += 512) {
      int n = idx >> 8, k = idx & (ED - 1);
      Wx[n][k] = Wih[((n >> 3) * HD + u0 + (n & 7)) * ED + k];
    }
    const float bia = bsum[0 * HD + u0 + eu];
    const float bif = bsum[1 * HD + u0 + eu];
    const float big = bsum[2 * HD + u0 + eu];
    const float bio = bsum[3 * HD + u0 + eu];
    float c = 0.f;
    __syncthreads();

    for (int t = 0; t < ST; ++t) {
      const int step = phase * ST + t;
      const bf16* hin = hbuf + (step & 1) * (NBAT * HD);
      bf16* hout      = hbuf + ((step & 1) ^ 1) * (NBAT * HD);
      const bf16* xin = Xall + t * (NBAT * ED);

      // ---- x-part first: independent of h, overlaps flag/h propagation ----
      f32x4 acc1 = {0.f, 0.f, 0.f, 0.f};
      #pragma unroll
      for (int kk = 0; kk < ED / 32; ++kk) {
        bf16x8 av = *(const bf16x8*)(xin + arow * ED + kk * 32 + kc);
        bf16x8 bv = *(const bf16x8*)(&Wx[brow][kk * 32 + kc]);
        acc1 = __builtin_amdgcn_mfma_f32_16x16x32_bf16(av, bv, acc1, 0, 0, 0);
      }

      // ---- wait for all blocks to have produced h(step) ----
      if (step > 0) {
        if (wid == 0) {
          u32 v = __hip_atomic_load(&flags[lane * 4], __ATOMIC_RELAXED,
                                    __HIP_MEMORY_SCOPE_AGENT);
          while (!__all((int)(v >= (u32)step))) {
            __builtin_amdgcn_s_sleep(1);
            v = __hip_atomic_load(&flags[lane * 4], __ATOMIC_RELAXED,
                                  __HIP_MEMORY_SCOPE_AGENT);
          }
          __threadfence();  // agent-scope inv: make remote h visible
        }
        __syncthreads();
      }

      // ---- h-part: gates += h(step) @ Whh^T ----
      f32x4 acc0 = {0.f, 0.f, 0.f, 0.f};
      #pragma unroll
      for (int kk = 0; kk < HD / 32; ++kk) {
        bf16x8 av = *(const bf16x8*)(hin + arow * HD + kk * 32 + kc);
        bf16x8 bv = *(const bf16x8*)(&Wr[brow][kk * 32 + kc]);
        acc0 = __builtin_amdgcn_mfma_f32_16x16x32_bf16(av, bv, acc0, 0, 0, 0);
      }
      #pragma unroll
      for (int r = 0; r < 4; ++r)
        gl[16 * wm + (lane >> 4) * 4 + r][16 * wn + r16] = acc0[r] + acc1[r];
      __syncthreads();

      // elementwise LSTM cell, one (b,u) per thread; c lives in a register
      float gi = gl[eb][eu]      + bia;
      float gf = gl[eb][8 + eu]  + bif;
      float gg = gl[eb][16 + eu] + big;
      float go = gl[eb][24 + eu] + bio;
      bool upd = (phase == 1) || (t < elen);
      float cn = sigm(gf) * c + sigm(gi) * tanhf(gg);
      float hn = sigm(go) * tanhf(cn);
      bf16 hv;
      if (upd) { c = cn; hv = (bf16)hn; } else { hv = hin[hidx]; }
      hout[hidx] = hv;
      if (phase == 1) hs[t * (NBAT * HD) + hidx] = hv;

      // ---- fire: publish h(step+1) ----
      if (step < 2 * ST - 1) {
        __syncthreads();  // drain all waves' h-stores (s_waitcnt vmcnt(0))
        if (tid == 0)
          __hip_atomic_store(&flags[blockIdx.x * 4], (u32)(step + 1),
                             __ATOMIC_RELEASE, __HIP_MEMORY_SCOPE_AGENT);
      }
    }
  }
}

// ---------------- output projection GEMM ----------------
// logits[b][t][v] = sum_h hs[t][b][h] * lin_W[v][h] + lin_b[v]
// M = ST*NBAT = 4096 (row m = t*64+b), N = VO = 32000, K = HD = 512.
// 128x128 tile, BK=64, 4 waves each owning a 64x64 quadrant (4x4 frags).
__global__ __launch_bounds__(256, 2) void k_logits(
    const bf16* __restrict__ hsb, const bf16* __restrict__ Wb,
    const float* __restrict__ linb, float* __restrict__ out)
{
  __shared__ __align__(16) bf16 As[128][72];  // +8 pad -> conflict-free frag reads
  __shared__ __align__(16) bf16 Bs[128][72];
  const int tid  = threadIdx.x;
  const int lane = tid & 63;
  const int wid  = tid >> 6;
  const int wm   = wid >> 1, wn = wid & 1;
  const int bn   = blockIdx.x * 128;
  const int bm   = blockIdx.y * 128;
  const int r16  = lane & 15, kh = lane >> 4;

  f32x4 acc[4][4];
  #pragma unroll
  for (int i = 0; i < 4; ++i)
    #pragma unroll
    for (int j = 0; j < 4; ++j) acc[i][j] = (f32x4){0.f, 0.f, 0.f, 0.f};

  const int srow = tid >> 3;        // 0..31
  const int scol = (tid & 7) * 8;   // 0..56

  for (int kt = 0; kt < HD / 64; ++kt) {
    __syncthreads();
    #pragma unroll
    for (int p = 0; p < 4; ++p) {
      int row = p * 32 + srow;
      *(bf16x8*)(&As[row][scol]) =
          *(const bf16x8*)(hsb + (size_t)(bm + row) * HD + kt * 64 + scol);
      *(bf16x8*)(&Bs[row][scol]) =
          *(const bf16x8*)(Wb + (size_t)(bn + row) * HD + kt * 64 + scol);
    }
    __syncthreads();
    #pragma unroll
    for (int kk = 0; kk < 2; ++kk) {
      bf16x8 af[4], bfv[4];
      #pragma unroll
      for (int i = 0; i < 4; ++i)
        af[i] = *(const bf16x8*)(&As[64 * wm + 16 * i + r16][kk * 32 + kh * 8]);
      #pragma unroll
      for (int j = 0; j < 4; ++j)
        bfv[j] = *(const bf16x8*)(&Bs[64 * wn + 16 * j + r16][kk * 32 + kh * 8]);
      #pragma unroll
      for (int i = 0; i < 4; ++i)
        #pragma unroll
        for (int j = 0; j < 4; ++j)
          acc[i][j] = __builtin_amdgcn_mfma_f32_16x16x32_bf16(af[i], bfv[j], acc[i][j], 0, 0, 0);
    }
  }

  #pragma unroll
  for (int j = 0; j < 4; ++j) {
    int ncol = bn + 64 * wn + 16 * j + r16;
    float bias = linb[ncol];
    #pragma unroll
    for (int i = 0; i < 4; ++i) {
      int mbase = bm + 64 * wm + 16 * i + kh * 4;
      #pragma unroll
      for (int r = 0; r < 4; ++r) {
        int m = mbase + r;
        int b = m & 63, t = m >> 6;
        out[(size_t)(b * ST + t) * VO + ncol] = acc[i][j][r] + bias;
      }
    }
  }
}

// ---------------- host ----------------

extern "C" void kernel_launch(void* const* d_in, const int* in_sizes, int n_in,
                              void* d_out, int out_size, void* d_ws, size_t ws_size,
                              hipStream_t stream) {
  const int*   toks = (const int*)d_in[0];
  const float* emb  = (const float*)d_in[1];
  const float* eWih = (const float*)d_in[2];
  const float* eWhh = (const float*)d_in[3];
  const float* ebih = (const float*)d_in[4];
  const float* ebhh = (const float*)d_in[5];
  const float* dWih = (const float*)d_in[6];
  const float* dWhh = (const float*)d_in[7];
  const float* dbih = (const float*)d_in[8];
  const float* dbhh = (const float*)d_in[9];
  const float* linW = (const float*)d_in[10];
  const float* linb = (const float*)d_in[11];
  float* out = (float*)d_out;

  char* ws = (char*)d_ws;
  size_t off = 0;
  auto alloc = [&](size_t bytes) {
    void* p = ws + off;
    off = (off + bytes + 255) & ~(size_t)255;
    return p;
  };
  bf16* encX  = (bf16*)alloc((size_t)ST * NBAT * ED * 2);
  bf16* decX  = (bf16*)alloc((size_t)ST * NBAT * ED * 2);
  bf16* WihEb = (bf16*)alloc((size_t)G4 * ED * 2);
  bf16* WhhEb = (bf16*)alloc((size_t)G4 * HD * 2);
  bf16* WihDb = (bf16*)alloc((size_t)G4 * ED * 2);
  bf16* WhhDb = (bf16*)alloc((size_t)G4 * HD * 2);
  bf16* WbL   = (bf16*)alloc((size_t)VO * HD * 2);
  float* bsumE = (float*)alloc(G4 * 4);
  float* bsumD = (float*)alloc(G4 * 4);
  bf16* hbuf  = (bf16*)alloc((size_t)2 * NBAT * HD * 2);
  bf16* hs    = (bf16*)alloc((size_t)ST * NBAT * HD * 2);
  int*  len   = (int*)alloc(NBAT * 4);
  u32*  flags = (u32*)alloc(1024);

  hipMemsetAsync(hbuf, 0, (size_t)2 * NBAT * HD * 2, stream);
  hipMemsetAsync(flags, 0, 1024, stream);

  k_lengths<<<1, 64, 0, stream>>>(toks, len);
  k_bias<<<(G4 + 255) / 256, 256, 0, stream>>>(ebih, ebhh, bsumE);
  k_bias<<<(G4 + 255) / 256, 256, 0, stream>>>(dbih, dbhh, bsumD);
  k_cast<<<(G4 * ED + 255) / 256, 256, 0, stream>>>(eWih, WihEb, G4 * ED);
  k_cast<<<(G4 * HD + 255) / 256, 256, 0, stream>>>(eWhh, WhhEb, G4 * HD);
  k_cast<<<(G4 * ED + 255) / 256, 256, 0, stream>>>(dWih, WihDb, G4 * ED);
  k_cast<<<(G4 * HD + 255) / 256, 256, 0, stream>>>(dWhh, WhhDb, G4 * HD);
  k_cast<<<(VO * HD + 255) / 256, 256, 0, stream>>>(linW, WbL, VO * HD);
  k_gather<<<(ST * NBAT * ED + 255) / 256, 256, 0, stream>>>(toks, emb, encX, decX);

  k_lstm<<<LSTM_BLOCKS, 512, 0, stream>>>(encX, decX, WihEb, WhhEb, WihDb, WhhDb,
                                          bsumE, bsumD, len, hbuf, hs, flags);

  k_logits<<<dim3(VO / 128, (ST * NBAT) / 128), 256, 0, stream>>>(hs, WbL, linb, out);
}